// Round 1
// baseline (364.762 us; speedup 1.0000x reference)
//
#include <hip/hip_runtime.h>

#define DEVI __device__ __forceinline__

typedef unsigned short u16;
typedef unsigned int   u32;
typedef __attribute__((ext_vector_type(4))) float f32x4;
typedef __attribute__((ext_vector_type(8))) short short8;
typedef __attribute__((ext_vector_type(8))) __bf16 bf16x8;

#define B_   2
#define S_   2048
#define H_   2048
#define NH_  16
#define HD_  128
#define BH_  (B_*NH_)
#define QSCALE 0.08838834764831845f   // 1/sqrt(128)

DEVI u16 f2b(float f){                       // f32 -> bf16 bits, RNE
  u32 u = __builtin_bit_cast(u32, f);
  u32 r = (u + 0x7fffu + ((u >> 16) & 1u)) >> 16;
  return (u16)r;
}
DEVI float b2f(u16 h){
  u32 u = ((u32)h) << 16;
  return __builtin_bit_cast(float, u);
}
DEVI f32x4 mfma_bf16(short8 a, short8 b, f32x4 c){
  return __builtin_amdgcn_mfma_f32_16x16x32_bf16(
      __builtin_bit_cast(bf16x8, a), __builtin_bit_cast(bf16x8, b), c, 0, 0, 0);
}
DEVI void gl_lds16(const void* g, void* l){
  __builtin_amdgcn_global_load_lds((const __attribute__((address_space(1))) void*)g,
                                   (__attribute__((address_space(3))) void*)l, 16, 0, 0);
}

// Stage a 16KB tile (1024 x 16B chunks) into LDS with XOR swizzle applied on the
// GLOBAL source column (LDS dest stays linear; read side applies the same XOR).
// LOG2CPR = log2(16B chunks per row). Row byte-stride = (1<<LOG2CPR)*16.
template<int LOG2CPR>
DEVI void stage_swz(const u16* __restrict__ src, int srcStride /*elems*/, u16* lds, int tid){
  const int wid = tid >> 6, lane = tid & 63;
#pragma unroll
  for (int i = 0; i < 4; ++i){
    int lin = i*256 + wid*64 + lane;                       // 16B chunk index
    int row = lin >> LOG2CPR;
    int cb  = ((lin & ((1 << LOG2CPR) - 1)) * 16) ^ ((row & 7) << 4);
    gl_lds16(src + (size_t)row * srcStride + (cb >> 1),
             lds + (size_t)(i*256 + wid*64) * 8);          // wave-uniform LDS base
  }
}

// ---------------- f32 -> bf16 convert ----------------
__global__ __launch_bounds__(256) void cvt_kernel(const float* __restrict__ src,
                                                  u16* __restrict__ dst, int n4){
  int i = blockIdx.x * 256 + threadIdx.x;
  if (i >= n4) return;
  float4 v = ((const float4*)src)[i];
  u32 lo = (u32)f2b(v.x) | ((u32)f2b(v.y) << 16);
  u32 hi = (u32)f2b(v.z) | ((u32)f2b(v.w) << 16);
  uint2 o; o.x = lo; o.y = hi;
  ((uint2*)dst)[i] = o;
}

// ---------------- GEMM C = A * B^T  (A [M][K] bf16 rm, Bw [N][K] bf16 rm) ----------------
// 128x128 tile, BK=64, 256 threads (4 waves 2x2, each 64x64), mfma 16x16x32 bf16.
// EPI 0: write f32 to C [M][N].   EPI 1: scatter bf16 into Q/K/V [B,NH,S,HD].
template<int EPI>
__global__ __launch_bounds__(256) void gemm_bt(
    const u16* __restrict__ A, const u16* __restrict__ Bw,
    float* __restrict__ C, u16* __restrict__ Qd, u16* __restrict__ Kd, u16* __restrict__ Vd,
    int M, int N, int K)
{
  __shared__ __align__(16) u16 As[128*64];
  __shared__ __align__(16) u16 Bs[128*64];
  const int tid  = threadIdx.x, lane = tid & 63, wid = tid >> 6;
  const int wr   = wid >> 1, wc = wid & 1;
  const int lrow = lane & 15, lk = lane >> 4;
  const int RB = blockIdx.y * 128, CB = blockIdx.x * 128;
  f32x4 acc[4][4] = {};

  for (int k0 = 0; k0 < K; k0 += 64){
    __syncthreads();
    stage_swz<3>(A  + (size_t)RB * K + k0, K, As, tid);
    stage_swz<3>(Bw + (size_t)CB * K + k0, K, Bs, tid);
    __syncthreads();
#pragma unroll
    for (int kk = 0; kk < 2; ++kk){
      short8 af[4], bf[4];
#pragma unroll
      for (int m = 0; m < 4; ++m){
        int row = wr*64 + m*16 + lrow;
        int cb  = (kk*64 + lk*16) ^ ((row & 7) << 4);
        af[m] = *(const short8*)&As[row*64 + (cb >> 1)];
      }
#pragma unroll
      for (int n = 0; n < 4; ++n){
        int row = wc*64 + n*16 + lrow;
        int cb  = (kk*64 + lk*16) ^ ((row & 7) << 4);
        bf[n] = *(const short8*)&Bs[row*64 + (cb >> 1)];
      }
#pragma unroll
      for (int m = 0; m < 4; ++m)
#pragma unroll
        for (int n = 0; n < 4; ++n)
          acc[m][n] = mfma_bf16(af[m], bf[n], acc[m][n]);
    }
  }

#pragma unroll
  for (int m = 0; m < 4; ++m){
#pragma unroll
    for (int n = 0; n < 4; ++n){
#pragma unroll
      for (int r = 0; r < 4; ++r){
        int row = RB + wr*64 + m*16 + lk*4 + r;
        int col = CB + wc*64 + n*16 + lrow;
        float v = acc[m][n][r];
        if constexpr (EPI == 0){
          C[(size_t)row * N + col] = v;
        } else {
          int which = col >> 11;
          int hd = col & 2047;
          int h = hd >> 7, d = hd & 127;
          int b = row >> 11, s = row & 2047;
          u16* dst = (which == 0) ? Qd : (which == 1) ? Kd : Vd;
          dst[(((size_t)(b*NH_ + h)) * S_ + s) * HD_ + d] = f2b(v);
        }
      }
    }
  }
}

// ---------------- RoPE (in place on Q,K [BH,S,HD]; Q also scaled by 1/sqrt(HD)) ----------------
__global__ __launch_bounds__(256) void rope_kernel(u16* __restrict__ Q, u16* __restrict__ K,
                                                   const float* __restrict__ F){
  int idx = blockIdx.x * 256 + threadIdx.x;   // BH*S*64
  int d2 = idx & 63;
  int s  = (idx >> 6) & (S_ - 1);
  int bh = idx >> 17;
  size_t off = ((size_t)bh * S_ + s) * HD_ + d2*2;
  float c = F[s*128 + d2*2], sn = F[s*128 + d2*2 + 1];
  u32 qp = *(const u32*)(Q + off);
  float tr = b2f((u16)qp), ti = b2f((u16)(qp >> 16));
  float q0 = (tr*c - ti*sn) * QSCALE, q1 = (tr*sn + ti*c) * QSCALE;
  *(u32*)(Q + off) = (u32)f2b(q0) | ((u32)f2b(q1) << 16);
  u32 kp = *(const u32*)(K + off);
  tr = b2f((u16)kp); ti = b2f((u16)(kp >> 16));
  float k0 = tr*c - ti*sn, k1 = tr*sn + ti*c;
  *(u32*)(K + off) = (u32)f2b(k0) | ((u32)f2b(k1) << 16);
}

// ---------------- V transpose: [BH,S,HD] -> [BH,HD,S] ----------------
__global__ void transpose_v(const u16* __restrict__ V, u16* __restrict__ Vt){
  __shared__ u16 t[32][33];
  int s0 = blockIdx.x * 32, d0 = blockIdx.y * 32, bh = blockIdx.z;
  const u16* vb = V  + (size_t)bh * S_ * HD_;
  u16*       tb = Vt + (size_t)bh * HD_ * S_;
  int tx = threadIdx.x, ty = threadIdx.y;
#pragma unroll
  for (int i = 0; i < 4; ++i)
    t[ty + i*8][tx] = vb[(size_t)(s0 + ty + i*8) * HD_ + d0 + tx];
  __syncthreads();
#pragma unroll
  for (int i = 0; i < 4; ++i)
    tb[(size_t)(d0 + ty + i*8) * S_ + s0 + tx] = t[tx][ty + i*8];
}

// ---------------- Flash attention (causal), QBLK=64 (4 waves x16 rows), KVBLK=64 ----------------
__global__ __launch_bounds__(256) void attn_kernel(
    const u16* __restrict__ Q, const u16* __restrict__ K, const u16* __restrict__ Vt,
    u16* __restrict__ O)
{
  __shared__ __align__(16) u16 Ks[64*128];   // [kv][d], swizzled
  __shared__ __align__(16) u16 Vs[128*64];   // [d][kv], swizzled
  __shared__ __align__(16) u16 Ps[4][16*72]; // per-wave P tile [16 q][64 kv], pad->72
  const int tid  = threadIdx.x, lane = tid & 63, wid = tid >> 6;
  const int lrow = lane & 15, lk = lane >> 4;
  const int bh = blockIdx.y;
  const int q0 = (gridDim.x - 1 - blockIdx.x) * 64;  // heavy tiles first

  short8 qf[4];
  {
    const u16* qb = Q + ((size_t)bh * S_ + q0 + wid*16 + lrow) * HD_;
#pragma unroll
    for (int kc = 0; kc < 4; ++kc) qf[kc] = *(const short8*)&qb[kc*32 + lk*8];
  }
  f32x4 acco[8] = {};
  float m_[4], l_[4];
#pragma unroll
  for (int r = 0; r < 4; ++r){ m_[r] = -3.0e38f; l_[r] = 0.0f; }

  for (int kv0 = 0; kv0 <= q0; kv0 += 64){
    __syncthreads();
    stage_swz<4>(K  + ((size_t)bh * S_ + kv0) * HD_, HD_, Ks, tid);
    stage_swz<3>(Vt + (size_t)bh * HD_ * S_ + kv0,   S_,  Vs, tid);
    __syncthreads();

    f32x4 sc[4];
#pragma unroll
    for (int nt = 0; nt < 4; ++nt){
      f32x4 a = {0.f, 0.f, 0.f, 0.f};
#pragma unroll
      for (int kc = 0; kc < 4; ++kc){
        int row = nt*16 + lrow;
        int cb  = (kc*64 + lk*16) ^ ((row & 7) << 4);
        short8 kf = *(const short8*)&Ks[row*128 + (cb >> 1)];
        a = mfma_bf16(qf[kc], kf, a);
      }
      sc[nt] = a;
    }
    if (kv0 == q0){   // diagonal tile: causal mask
#pragma unroll
      for (int nt = 0; nt < 4; ++nt){
        int kvc = nt*16 + lrow;
#pragma unroll
        for (int r = 0; r < 4; ++r){
          int qr = wid*16 + lk*4 + r;
          if (kvc > qr) sc[nt][r] = -3.0e38f;
        }
      }
    }
    float corr[4];
#pragma unroll
    for (int r = 0; r < 4; ++r){
      float mt = fmaxf(fmaxf(sc[0][r], sc[1][r]), fmaxf(sc[2][r], sc[3][r]));
#pragma unroll
      for (int d = 1; d < 16; d <<= 1) mt = fmaxf(mt, __shfl_xor(mt, d, 16));
      float mn = fmaxf(m_[r], mt);
      corr[r] = __expf(m_[r] - mn);
      float rs = 0.f;
#pragma unroll
      for (int nt = 0; nt < 4; ++nt){
        float p = __expf(sc[nt][r] - mn);
        sc[nt][r] = p;
        rs += p;
      }
#pragma unroll
      for (int d = 1; d < 16; d <<= 1) rs += __shfl_xor(rs, d, 16);
      l_[r] = l_[r] * corr[r] + rs;
      m_[r] = mn;
    }
#pragma unroll
    for (int dt = 0; dt < 8; ++dt)
#pragma unroll
      for (int r = 0; r < 4; ++r) acco[dt][r] *= corr[r];

    u16* pb = Ps[wid];
#pragma unroll
    for (int nt = 0; nt < 4; ++nt)
#pragma unroll
      for (int r = 0; r < 4; ++r)
        pb[(lk*4 + r)*72 + nt*16 + lrow] = f2b(sc[nt][r]);
    asm volatile("" ::: "memory");  // keep P writes before P reads (same-wave LDS is HW-ordered)

    short8 pf[2];
#pragma unroll
    for (int kc2 = 0; kc2 < 2; ++kc2)
      pf[kc2] = *(const short8*)&pb[lrow*72 + kc2*32 + lk*8];
#pragma unroll
    for (int dt = 0; dt < 8; ++dt){
#pragma unroll
      for (int kc2 = 0; kc2 < 2; ++kc2){
        int row = dt*16 + lrow;
        int cb  = (kc2*64 + lk*16) ^ ((row & 7) << 4);
        short8 vf = *(const short8*)&Vs[row*64 + (cb >> 1)];
        acco[dt] = mfma_bf16(pf[kc2], vf, acco[dt]);
      }
    }
  }

  const int b = bh >> 4, h = bh & 15;
#pragma unroll
  for (int r = 0; r < 4; ++r) l_[r] = 1.0f / l_[r];
#pragma unroll
  for (int dt = 0; dt < 8; ++dt)
#pragma unroll
    for (int r = 0; r < 4; ++r){
      int row = q0 + wid*16 + lk*4 + r;
      int col = h*128 + dt*16 + lrow;
      O[((size_t)(b*S_ + row)) * H_ + col] = f2b(acco[dt][r] * l_[r]);
    }
}

// ---------------- launch ----------------
extern "C" void kernel_launch(void* const* d_in, const int* in_sizes, int n_in,
                              void* d_out, int out_size, void* d_ws, size_t ws_size,
                              hipStream_t stream)
{
  (void)in_sizes; (void)n_in; (void)out_size; (void)ws_size;
  const float* x  = (const float*)d_in[0];
  const float* fc = (const float*)d_in[1];   // freqs_cis [S,64,2]
  const float* wq = (const float*)d_in[3];
  const float* wk = (const float*)d_in[4];
  const float* wv = (const float*)d_in[5];
  const float* wo = (const float*)d_in[6];
  // position_ids (d_in[7]) == arange(S) broadcast; used implicitly.

  char* w = (char*)d_ws;
  u16* xb   = (u16*)(w);                 // [4096,2048] bf16   16.78 MB
  u16* wqkv = (u16*)(w + 16777216);      // [6144,2048] bf16   25.17 MB
  u16* wob  = (u16*)(w + 41943040);      // [2048,2048] bf16    8.39 MB
  u16* Qr   = (u16*)(w + 50331648);      // [BH,S,HD]   bf16   16.78 MB
  u16* Kr   = (u16*)(w + 67108864);      // [BH,S,HD]   bf16
  u16* Vr   = (u16*)(w + 83886080);      // [BH,S,HD]   bf16
  u16* Vt   = (u16*)(w + 100663296);     // [BH,HD,S]   bf16
  u16* aO   = (u16*)(w + 117440512);     // [4096,2048] bf16 (attn out, [B,S,H])
  float* out = (float*)d_out;

  cvt_kernel<<<8192, 256, 0, stream>>>(x,  xb,             2097152);
  cvt_kernel<<<4096, 256, 0, stream>>>(wq, wqkv,           1048576);
  cvt_kernel<<<4096, 256, 0, stream>>>(wk, wqkv + 4194304, 1048576);
  cvt_kernel<<<4096, 256, 0, stream>>>(wv, wqkv + 8388608, 1048576);
  cvt_kernel<<<4096, 256, 0, stream>>>(wo, wob,            1048576);

  gemm_bt<1><<<dim3(48, 32), 256, 0, stream>>>(xb, wqkv, nullptr, Qr, Kr, Vr, 4096, 6144, 2048);
  rope_kernel<<<16384, 256, 0, stream>>>(Qr, Kr, fc);
  transpose_v<<<dim3(64, 4, 32), dim3(32, 8), 0, stream>>>(Vr, Vt);
  attn_kernel<<<dim3(32, 32), 256, 0, stream>>>(Qr, Kr, Vt, aO);
  gemm_bt<0><<<dim3(16, 32), 256, 0, stream>>>(aO, wob, out, nullptr, nullptr, nullptr, 4096, 2048, 2048);
}